// Round 20
// baseline (129.892 us; speedup 1.0000x reference)
//
#include <hip/hip_runtime.h>

#define BB 2048
#define NTH 768
#define NN 1023
#define NI 10
#define NPASS 10
#define DUMMY 1023
#define MAXSLOTS 1072
#define LOG2E 1.44269504f
#define LN2 0.69314718f
#define SBYTES 28672          // one state buffer: 1024 rows x 7 dwords (28 B, gcd(7,32)=1)

typedef _Float16 half2v __attribute__((ext_vector_type(2)));
typedef _Float16 half8v __attribute__((ext_vector_type(8)));
typedef __fp16   fp16x2 __attribute__((ext_vector_type(2)));
typedef float    floatx4 __attribute__((ext_vector_type(4)));
typedef unsigned int uint;
typedef unsigned long long ull;

#if __has_builtin(__builtin_amdgcn_exp2f)
#define EXP2(x) __builtin_amdgcn_exp2f(x)
#else
#define EXP2(x) exp2f(x)
#endif
#if __has_builtin(__builtin_amdgcn_rcpf)
#define RCP(x) __builtin_amdgcn_rcpf(x)
#else
#define RCP(x) (1.f / (x))
#endif

// Butterfly reduce over lanes {l, l^16, l^32, l^48} via gfx950 permlane swaps
// (VALU, ~5cy) instead of ds_bpermute round-trips (~60cy) on the critical path.
#if __has_builtin(__builtin_amdgcn_permlane16_swap) && __has_builtin(__builtin_amdgcn_permlane32_swap)
#define REDUCE16_32(PART) {                                                      \
    union { float f; uint u; } _c; _c.f = (PART);                                \
    auto _r1 = __builtin_amdgcn_permlane16_swap(_c.u, _c.u, false, false);       \
    union { uint u; float f; } _a, _b;                                           \
    _a.u = _r1[0]; _b.u = _r1[1];                                                \
    _c.f = _a.f + _b.f;                                                          \
    auto _r2 = __builtin_amdgcn_permlane32_swap(_c.u, _c.u, false, false);       \
    _a.u = _r2[0]; _b.u = _r2[1];                                                \
    (PART) = _a.f + _b.f;                                                        \
}
#else
#define REDUCE16_32(PART) {                                                      \
    (PART) += __shfl_xor((PART), 16);                                            \
    (PART) += __shfl_xor((PART), 32);                                            \
}
#endif

static __device__ inline uint pkh(float a, float b) {
#if __has_builtin(__builtin_amdgcn_cvt_pkrtz)
    union { fp16x2 h; uint u; } z;
    z.h = __builtin_amdgcn_cvt_pkrtz(a, b);
    return z.u;
#else
    union { uint u; _Float16 h[2]; } z;
    z.h[0] = (_Float16)a; z.h[1] = (_Float16)b; return z.u;
#endif
}

static __device__ inline half2v h2(uint u) {
    union { uint u; half2v h; } z; z.u = u; return z.h;
}

static __device__ inline bool getmask(const void* mraw, bool mbytes, long idx) {
    return mbytes ? (((const unsigned char*)mraw)[idx] != 0)
                  : (((const int*)mraw)[idx] != 0);
}

// T fragments: [op*5+q][lane] uint4 = half8; slot e: i = 5*(g>>1)+q,
// j = 8*(g&1)+e, value T[op][i][j][col] * log2(e)
__global__ __launch_bounds__(64) void prepack_kernel(const float* __restrict__ op_table,
                                                     uint4* __restrict__ tpk) {
    int lane = threadIdx.x;
    int opq  = blockIdx.x;              // 0..14
    int op = opq / 5, q = opq % 5;
    int col = lane & 15, g = lane >> 4, hi = g >> 1, jh = (g & 1) * 8;
    union { uint4 u; _Float16 h[8]; } z;
    #pragma unroll
    for (int e = 0; e < 8; ++e) {
        int i = 5 * hi + q, j = jh + e;
        float v = 0.f;
        if (col < NI && j < NI) v = op_table[op * 1000 + (i * NI + j) * NI + col] * LOG2E;
        z.h[e] = (_Float16)v;
    }
    tpk[opq * 64 + lane] = z.u;
}

template <int MODE>   // 1 = prepacked T in ws; 0 = self-contained
__global__ __launch_bounds__(NTH, 6)
void circuit_kernel(const float* __restrict__ op_table,
                    const int* __restrict__ cats,
                    const int* __restrict__ ops,
                    const int* __restrict__ lits,
                    const int* __restrict__ left,
                    const int* __restrict__ right,
                    const void* __restrict__ mask_raw,
                    float* __restrict__ out,
                    const uint4* __restrict__ tpk)
{
    // two state buffers, rows of 7 dwords (halves 0-9 data, 10-13 zero pad),
    // + 8 zero-pad dwords so overflow reads stay finite.
    __shared__ __align__(16) uint sS[2 * 7168 + 8];   // 57,376 B
    __shared__ uint sBkt[MAXSLOTS];                   //  4,288 B
    __shared__ int sCtl[16];

    const int b    = blockIdx.x;
    const int tid  = threadIdx.x;
    const int lane = tid & 63;
    const int wave = tid >> 6;          // 0..11
    const int myOp = wave >> 2;         // 0..2 (4 waves per op, static)
    const int wl   = wave & 3;
    const int col  = lane & 15;         // node-in-tile (D col)
    const int g    = lane >> 4;         // k-quadrant (D rows 4g..4g+3)
    const int hi   = g >> 1;            // i-block: i = 5*hi + q
    const int jh   = (g & 1) * 8;       // j-block: j = jh + e
    const long rowoff = (long)b * NN;

    const uint mw0 = *(const uint*)mask_raw;
    const bool mbytes = (mw0 == 0x01010101u);

    if (tid < 16) sCtl[tid] = 0;
    if (tid < 8) sS[14336 + tid] = 0;

    // per-lane byte selectors for v_perm l-extraction (pass-invariant)
    const uint selA = hi ? 0x03020302u : 0x01000100u;   // q = 0,2,4
    const uint selB = hi ? 0x05040504u : 0x03020302u;   // q = 1,3

    // ---- per-wave single-op T fragments ----
    half8v Tf[5];
    if constexpr (MODE == 1) {
        #pragma unroll
        for (int q = 0; q < 5; ++q) {
            union { uint4 u; half8v h; } z;
            z.u = tpk[(myOp * 5 + q) * 64 + lane];
            Tf[q] = z.h;
        }
    } else {
        #pragma unroll
        for (int q = 0; q < 5; ++q) {
            half8v t_;
            #pragma unroll
            for (int e = 0; e < 8; ++e) {
                int i = 5 * hi + q, j = jh + e;
                float v = 0.f;
                if (col < NI && j < NI)
                    v = op_table[myOp * 1000 + (i * NI + j) * NI + col] * LOG2E;
                t_[e] = (_Float16)v;
            }
            Tf[q] = t_;
        }
    }

    // ---- init state rows (both buffers) + capture node info (2 nodes/thread) ----
    int  myop0 = 3, myop1 = 3;
    uint enc0 = 0, enc1 = 0;
    #define INIT_NODE(N, MYOP, ENC)                                              \
    {                                                                            \
        int n = (N);                                                             \
        uint r[7] = {0, 0, 0, 0, 0, 0, 0};                                       \
        if (n < NN) {                                                            \
            int cat = cats[rowoff + n];                                          \
            int lit = lits[rowoff + n];                                          \
            int op  = ops[rowoff + n];                                           \
            int lf  = left[rowoff + n];                                          \
            int rt  = right[rowoff + n];                                         \
            bool m  = getmask(mask_raw, mbytes, rowoff + n);                     \
            lit = min(max(lit, 0), NI - 1);                                      \
            op  = min(max(op, 0), 2);                                            \
            lf  = min(max(lf, 0), NN - 1);                                       \
            rt  = min(max(rt, 0), NN - 1);                                       \
            if (cat == 0 && m) {                                                 \
                r[lit >> 1] = (lit & 1) ? 0x3C000000u : 0x3C00u;                 \
            } else if (cat == 1 && m) {                                          \
                MYOP = op;                                                       \
                ENC = (uint)n | ((uint)lf << 10) | ((uint)rt << 20);             \
            }                                                                    \
        }                                                                        \
        if (n < 1024) {                                                          \
            _Pragma("unroll")                                                    \
            for (int w = 0; w < 7; ++w) {                                        \
                sS[n * 7 + w] = r[w];                                            \
                sS[7168 + n * 7 + w] = r[w];                                     \
            }                                                                    \
        }                                                                        \
    }
    INIT_NODE(tid, myop0, enc0)
    INIT_NODE(tid + NTH, myop1, enc1)
    __syncthreads();

    // ---- ballot counting (1 atomic per op per wave) ----
    {
        ull m00 = __ballot(myop0 == 0), m01 = __ballot(myop0 == 1), m02 = __ballot(myop0 == 2);
        ull m10 = __ballot(myop1 == 0), m11 = __ballot(myop1 == 1), m12 = __ballot(myop1 == 2);
        int c0 = __popcll(m00) + __popcll(m10);
        int c1 = __popcll(m01) + __popcll(m11);
        int c2 = __popcll(m02) + __popcll(m12);
        if (lane == 0) {
            if (c0) atomicAdd(&sCtl[0], c0);
            if (c1) atomicAdd(&sCtl[1], c1);
            if (c2) atomicAdd(&sCtl[2], c2);
        }
    }
    __syncthreads();
    if (tid == 0) {
        int c0 = sCtl[0], c1 = sCtl[1], c2 = sCtl[2];
        int p0 = (c0 + 15) & ~15, p1 = (c1 + 15) & ~15, p2 = (c2 + 15) & ~15;
        sCtl[4] = p0; sCtl[5] = p0 + p1; sCtl[9] = p0 + p1 + p2;
        sCtl[6] = 0; sCtl[7] = p0; sCtl[8] = p0 + p1;   // cursors
    }
    __syncthreads();
    // ---- ballot placement ----
    #define PLACE(MYOP, ENC)                                                     \
    {                                                                            \
        _Pragma("unroll")                                                        \
        for (int o = 0; o < 3; ++o) {                                            \
            ull mm = __ballot((MYOP) == o);                                      \
            if (mm) {                                                            \
                int rsv = 0;                                                     \
                if (lane == 0) rsv = atomicAdd(&sCtl[6 + o], __popcll(mm));      \
                rsv = __shfl(rsv, 0);                                            \
                if ((MYOP) == o)                                                 \
                    sBkt[rsv + __popcll(mm & ((1ull << lane) - 1))] = (ENC);     \
            }                                                                    \
        }                                                                        \
    }
    PLACE(myop0, enc0)
    PLACE(myop1, enc1)
    __syncthreads();
    // ---- dummy-fill bucket tails ----
    {
        uint dv = (uint)DUMMY | ((uint)DUMMY << 10) | ((uint)DUMMY << 20);
        int f0 = sCtl[6], e0b = sCtl[4];
        int f1 = sCtl[7], e1b = sCtl[5];
        int f2 = sCtl[8], e2b = sCtl[9];
        if (tid < e0b - f0) sBkt[f0 + tid] = dv;
        if (tid < e1b - f1) sBkt[f1 + tid] = dv;
        if (tid < e2b - f2) sBkt[f2 + tid] = dv;
    }
    __syncthreads();

    const int tB1 = __builtin_amdgcn_readfirstlane(sCtl[4] >> 4);
    const int tB2 = __builtin_amdgcn_readfirstlane(sCtl[5] >> 4);
    const int tB3 = __builtin_amdgcn_readfirstlane(sCtl[9] >> 4);
    const int t_lo = (myOp == 0) ? 0   : ((myOp == 1) ? tB1 : tB2);
    const int t_hi = (myOp == 0) ? tB1 : ((myOp == 1) ? tB2 : tB3);
    const int first = t_lo + wl;
    const int nIter = (t_hi > first) ? ((t_hi - first + 3) >> 2) : 0;
    const int cat0 = cats[rowoff];
    const bool rootActive = (cat0 == 1) && getmask(mask_raw, mbytes, rowoff);

    // ---- cache <=3 iters of pass-invariant decoded byte offsets ----
    // Defaults 0 -> safe LDS addresses for the unconditional load phase.
    uint LA0 = 0, RA0 = 0, WA0 = 0, LA1 = 0, RA1 = 0, WA1 = 0, LA2 = 0, RA2 = 0, WA2 = 0;
    bool RT0 = false, RT1 = false, RT2 = false;
    #define CACHE1(K, LA, RA, WA, RT)                                            \
    if (nIter > K) {                                                             \
        uint E = sBkt[(first + K * 4) * 16 + col];                               \
        uint n_ = E & 1023u, lf_ = (E >> 10) & 1023u, rt_ = (E >> 20) & 1023u;   \
        LA = lf_ * 28u + 8u * (uint)hi;                                          \
        RA = rt_ * 28u + 2u * (uint)jh;                                          \
        WA = n_ * 28u + 8u * (uint)g;                                            \
        RT = (n_ == 0u);                                                         \
    }
    CACHE1(0, LA0, RA0, WA0, RT0)
    CACHE1(1, LA1, RA1, WA1, RT1)
    CACHE1(2, LA2, RA2, WA2, RT2)

    char* sbase = (char*)&sS[0];

    #define MSTQ(QI, LU) {                                                       \
        half2v l2v = h2(LU);                                                     \
        union { half8v v8; half2v v2[4]; } au;                                   \
        au.v2[0] = l2v * R0; au.v2[1] = l2v * R1;                                \
        au.v2[2] = l2v * R2; au.v2[3] = l2v * R3;                                \
        C = __builtin_amdgcn_mfma_f32_16x16x32_f16(Tf[QI], au.v8, C, 0, 0, 0);   \
    }
    // unconditional load phase (addresses are always valid LDS)
    #define LOADI(LA, RA, VD0, VD1, VD2, VR0, VR1, VR2, VR3)                     \
        {                                                                        \
            const uint* lpd = (const uint*)(rbase + (LA));                       \
            const uint* rp  = (const uint*)(rbase + (RA));                       \
            VD0 = lpd[0]; VD1 = lpd[1]; VD2 = lpd[2];                            \
            VR0 = rp[0]; VR1 = rp[1]; VR2 = rp[2]; VR3 = rp[3];                  \
        }
    // compute on preloaded regs: softmax + state write
    #define COMP_BODY(VD0, VD1, VD2, VR0, VR1, VR2, VR3, WA)                     \
    {                                                                            \
        half2v R0 = h2(VR0), R1 = h2(VR1), R2 = h2(VR2), R3 = h2(VR3);           \
        uint L0 = __builtin_amdgcn_perm(VD0, VD0, selA);                         \
        uint L1 = __builtin_amdgcn_perm(VD1, VD0, selB);                         \
        uint L2 = __builtin_amdgcn_perm(VD1, VD1, selA);                         \
        uint L3 = __builtin_amdgcn_perm(VD2, VD1, selB);                         \
        uint L4 = __builtin_amdgcn_perm(VD2, VD2, selA);                         \
        floatx4 C = {0.f, 0.f, 0.f, 0.f};                                        \
        MSTQ(0, L0) MSTQ(1, L1) MSTQ(2, L2) MSTQ(3, L3) MSTQ(4, L4)              \
        float e0 = 0.f, e1 = 0.f, e2 = 0.f, e3 = 0.f, part;                      \
        if (g < 2) {                                                             \
            e0 = EXP2(C[0]); e1 = EXP2(C[1]); e2 = EXP2(C[2]); e3 = EXP2(C[3]);  \
            part = (e0 + e1) + (e2 + e3);                                        \
        } else if (g == 2) {                                                     \
            e0 = EXP2(C[0]); e1 = EXP2(C[1]); part = e0 + e1;                    \
        } else part = 0.f;                                                       \
        REDUCE16_32(part)                                                        \
        float inv = RCP(part);                                                   \
        if (g < 2) {                                                             \
            uint* wp = (uint*)(wbase + (WA));                                    \
            wp[0] = pkh(e0 * inv, e1 * inv);                                     \
            wp[1] = pkh(e2 * inv, e3 * inv);                                     \
        } else if (g == 2) {                                                     \
            *(uint*)(wbase + (WA)) = pkh(e0 * inv, e1 * inv);                    \
        }                                                                        \
    }
    // final pass: logits only, root store
    #define ITER_LAST(LA, RA, RT)                                                \
    {                                                                            \
        const uint* lpd = (const uint*)(rbase + (LA));                           \
        const uint* rp  = (const uint*)(rbase + (RA));                           \
        uint D0 = lpd[0], D1 = lpd[1], D2 = lpd[2];                              \
        half2v R0 = h2(rp[0]), R1 = h2(rp[1]), R2 = h2(rp[2]), R3 = h2(rp[3]);   \
        uint L0 = __builtin_amdgcn_perm(D0, D0, selA);                           \
        uint L1 = __builtin_amdgcn_perm(D1, D0, selB);                           \
        uint L2 = __builtin_amdgcn_perm(D1, D1, selA);                           \
        uint L3 = __builtin_amdgcn_perm(D2, D1, selB);                           \
        uint L4 = __builtin_amdgcn_perm(D2, D2, selA);                           \
        floatx4 C = {0.f, 0.f, 0.f, 0.f};                                        \
        MSTQ(0, L0) MSTQ(1, L1) MSTQ(2, L2) MSTQ(3, L3) MSTQ(4, L4)              \
        if (RT) {                                                                \
            if (g < 2) {                                                         \
                out[b * NI + 4 * g + 0] = C[0] * LN2;                            \
                out[b * NI + 4 * g + 1] = C[1] * LN2;                            \
                out[b * NI + 4 * g + 2] = C[2] * LN2;                            \
                out[b * NI + 4 * g + 3] = C[3] * LN2;                            \
            } else if (g == 2) {                                                 \
                out[b * NI + 8] = C[0] * LN2;                                    \
                out[b * NI + 9] = C[1] * LN2;                                    \
            }                                                                    \
        }                                                                        \
    }

    for (int p = 0; p < NPASS - 1; ++p) {
        char* rbase = sbase + ((p & 1) ? SBYTES : 0);
        char* wbase = sbase + ((p & 1) ? 0 : SBYTES);

        // ---- batched load phase: all 3 iters' LDS reads issue together ----
        uint d00, d01, d02, r00, r01, r02, r03;
        uint d10, d11, d12, r10, r11, r12, r13;
        uint d20, d21, d22, r20, r21, r22, r23;
        LOADI(LA0, RA0, d00, d01, d02, r00, r01, r02, r03)
        LOADI(LA1, RA1, d10, d11, d12, r10, r11, r12, r13)
        LOADI(LA2, RA2, d20, d21, d22, r20, r21, r22, r23)

        if (nIter > 0) COMP_BODY(d00, d01, d02, r00, r01, r02, r03, WA0)
        if (nIter > 1) COMP_BODY(d10, d11, d12, r10, r11, r12, r13, WA1)
        if (nIter > 2) COMP_BODY(d20, d21, d22, r20, r21, r22, r23, WA2)
        for (int it = 3; it < nIter; ++it) {     // rare overflow
            uint E = sBkt[(first + it * 4) * 16 + col];
            uint n_ = E & 1023u, lf_ = (E >> 10) & 1023u, rt_ = (E >> 20) & 1023u;
            uint LAx = lf_ * 28u + 8u * (uint)hi;
            uint RAx = rt_ * 28u + 2u * (uint)jh;
            uint WAx = n_ * 28u + 8u * (uint)g;
            uint xd0, xd1, xd2, xr0, xr1, xr2, xr3;
            LOADI(LAx, RAx, xd0, xd1, xd2, xr0, xr1, xr2, xr3)
            COMP_BODY(xd0, xd1, xd2, xr0, xr1, xr2, xr3, WAx)
        }
        __syncthreads();   // single barrier per pass (ping-pong)
    }
    {
        // pass 9: reads buffer 1 (state after 9 updates); root logits only.
        // Only the tile containing node 0 has any side effect -> ballot skip.
        char* rbase = sbase + SBYTES;
        if (nIter > 0 && __ballot(RT0)) ITER_LAST(LA0, RA0, RT0)
        if (nIter > 1 && __ballot(RT1)) ITER_LAST(LA1, RA1, RT1)
        if (nIter > 2 && __ballot(RT2)) ITER_LAST(LA2, RA2, RT2)
        for (int it = 3; it < nIter; ++it) {
            uint E = sBkt[(first + it * 4) * 16 + col];
            uint n_ = E & 1023u, lf_ = (E >> 10) & 1023u, rt_ = (E >> 20) & 1023u;
            uint LAx = lf_ * 28u + 8u * (uint)hi;
            uint RAx = rt_ * 28u + 2u * (uint)jh;
            bool RTx = (n_ == 0u);
            if (__ballot(RTx)) ITER_LAST(LAx, RAx, RTx)
        }
    }

    // masked-out op-root: logits from state-after-9 (= buffer 1)
    if (cat0 == 1 && !rootActive && tid == 0) {
        int op0 = min(max(ops[rowoff], 0), 2);
        int lf0 = min(max(left[rowoff], 0), NN - 1);
        int rt0 = min(max(right[rowoff], 0), NN - 1);
        const _Float16* sh = (const _Float16*)((char*)sS + SBYTES);
        float acc[NI];
        #pragma unroll
        for (int k = 0; k < NI; ++k) acc[k] = 0.f;
        for (int i = 0; i < NI; ++i) {
            float li = (float)sh[lf0 * 14 + i];
            for (int j = 0; j < NI; ++j) {
                float w = li * (float)sh[rt0 * 14 + j];
                #pragma unroll
                for (int k = 0; k < NI; ++k)
                    acc[k] = fmaf(w, op_table[op0 * 1000 + (i * NI + j) * NI + k], acc[k]);
            }
        }
        #pragma unroll
        for (int k = 0; k < NI; ++k) out[b * NI + k] = acc[k];
    }

    // lit-cat root: init state persists (lit rows never rewritten)
    if (cat0 == 0 && tid < NI) {
        out[b * NI + tid] = (float)((const _Float16*)sS)[tid] * 10.f;
    }
}

extern "C" void kernel_launch(void* const* d_in, const int* in_sizes, int n_in,
                              void* d_out, int out_size, void* d_ws, size_t ws_size,
                              hipStream_t stream) {
    const float* op_table = (const float*)d_in[0];
    const int*   cats     = (const int*)d_in[1];
    const int*   ops      = (const int*)d_in[2];
    const int*   lits     = (const int*)d_in[3];
    const int*   left     = (const int*)d_in[4];
    const int*   right    = (const int*)d_in[5];
    const void*  mask     = d_in[6];
    float* out = (float*)d_out;

    const size_t tbytes = (size_t)15 * 64 * sizeof(uint4);   // 15,360

    if (ws_size >= tbytes) {
        uint4* tpk = (uint4*)d_ws;
        prepack_kernel<<<dim3(15), dim3(64), 0, stream>>>(op_table, tpk);
        circuit_kernel<1><<<dim3(BB), dim3(NTH), 0, stream>>>(
            op_table, cats, ops, lits, left, right, mask, out, tpk);
    } else {
        circuit_kernel<0><<<dim3(BB), dim3(NTH), 0, stream>>>(
            op_table, cats, ops, lits, left, right, mask, out, nullptr);
    }
}

// Round 21
// 118.707 us; speedup vs baseline: 1.0942x; 1.0942x over previous
//
#include <hip/hip_runtime.h>

#define BB 2048
#define NTH 768
#define NN 1023
#define NI 10
#define NPASS 10
#define DUMMY 1023
#define MAXSLOTS 1072
#define LOG2E 1.44269504f
#define LN2 0.69314718f
#define SBYTES 28672          // one state buffer: 1024 rows x 7 dwords (28 B, gcd(7,32)=1)

typedef _Float16 half2v __attribute__((ext_vector_type(2)));
typedef _Float16 half8v __attribute__((ext_vector_type(8)));
typedef __fp16   fp16x2 __attribute__((ext_vector_type(2)));
typedef float    floatx4 __attribute__((ext_vector_type(4)));
typedef unsigned int uint;
typedef unsigned long long ull;

#if __has_builtin(__builtin_amdgcn_exp2f)
#define EXP2(x) __builtin_amdgcn_exp2f(x)
#else
#define EXP2(x) exp2f(x)
#endif
#if __has_builtin(__builtin_amdgcn_rcpf)
#define RCP(x) __builtin_amdgcn_rcpf(x)
#else
#define RCP(x) (1.f / (x))
#endif

// Butterfly reduce over lanes {l, l^16, l^32, l^48} via gfx950 permlane swaps
// (VALU, ~5cy) instead of ds_bpermute round-trips (~60cy) on the critical path.
#if __has_builtin(__builtin_amdgcn_permlane16_swap) && __has_builtin(__builtin_amdgcn_permlane32_swap)
#define REDUCE16_32(PART) {                                                      \
    union { float f; uint u; } _c; _c.f = (PART);                                \
    auto _r1 = __builtin_amdgcn_permlane16_swap(_c.u, _c.u, false, false);       \
    union { uint u; float f; } _a, _b;                                           \
    _a.u = _r1[0]; _b.u = _r1[1];                                                \
    _c.f = _a.f + _b.f;                                                          \
    auto _r2 = __builtin_amdgcn_permlane32_swap(_c.u, _c.u, false, false);       \
    _a.u = _r2[0]; _b.u = _r2[1];                                                \
    (PART) = _a.f + _b.f;                                                        \
}
#else
#define REDUCE16_32(PART) {                                                      \
    (PART) += __shfl_xor((PART), 16);                                            \
    (PART) += __shfl_xor((PART), 32);                                            \
}
#endif

static __device__ inline uint pkh(float a, float b) {
#if __has_builtin(__builtin_amdgcn_cvt_pkrtz)
    union { fp16x2 h; uint u; } z;
    z.h = __builtin_amdgcn_cvt_pkrtz(a, b);
    return z.u;
#else
    union { uint u; _Float16 h[2]; } z;
    z.h[0] = (_Float16)a; z.h[1] = (_Float16)b; return z.u;
#endif
}

static __device__ inline half2v h2(uint u) {
    union { uint u; half2v h; } z; z.u = u; return z.h;
}

static __device__ inline bool getmask(const void* mraw, bool mbytes, long idx) {
    return mbytes ? (((const unsigned char*)mraw)[idx] != 0)
                  : (((const int*)mraw)[idx] != 0);
}

// T fragments: [op*5+q][lane] uint4 = half8; slot e: i = 5*(g>>1)+q,
// j = 8*(g&1)+e, value T[op][i][j][col] * log2(e)
__global__ __launch_bounds__(64) void prepack_kernel(const float* __restrict__ op_table,
                                                     uint4* __restrict__ tpk) {
    int lane = threadIdx.x;
    int opq  = blockIdx.x;              // 0..14
    int op = opq / 5, q = opq % 5;
    int col = lane & 15, g = lane >> 4, hi = g >> 1, jh = (g & 1) * 8;
    union { uint4 u; _Float16 h[8]; } z;
    #pragma unroll
    for (int e = 0; e < 8; ++e) {
        int i = 5 * hi + q, j = jh + e;
        float v = 0.f;
        if (col < NI && j < NI) v = op_table[op * 1000 + (i * NI + j) * NI + col] * LOG2E;
        z.h[e] = (_Float16)v;
    }
    tpk[opq * 64 + lane] = z.u;
}

template <int MODE>   // 1 = prepacked T in ws; 0 = self-contained
__global__ __launch_bounds__(NTH, 6)
void circuit_kernel(const float* __restrict__ op_table,
                    const int* __restrict__ cats,
                    const int* __restrict__ ops,
                    const int* __restrict__ lits,
                    const int* __restrict__ left,
                    const int* __restrict__ right,
                    const void* __restrict__ mask_raw,
                    float* __restrict__ out,
                    const uint4* __restrict__ tpk)
{
    // two state buffers, rows of 7 dwords (halves 0-9 data, 10-13 zero pad),
    // + 8 zero-pad dwords so overflow reads stay finite.
    __shared__ __align__(16) uint sS[2 * 7168 + 8];   // 57,376 B
    __shared__ uint sBkt[MAXSLOTS];                   //  4,288 B
    __shared__ int sCtl[16];

    const int b    = blockIdx.x;
    const int tid  = threadIdx.x;
    const int lane = tid & 63;
    const int wave = tid >> 6;          // 0..11
    const int myOp = wave >> 2;         // 0..2 (4 waves per op, static)
    const int wl   = wave & 3;
    const int col  = lane & 15;         // node-in-tile (D col)
    const int g    = lane >> 4;         // k-quadrant (D rows 4g..4g+3)
    const int hi   = g >> 1;            // i-block: i = 5*hi + q
    const int jh   = (g & 1) * 8;       // j-block: j = jh + e
    const long rowoff = (long)b * NN;

    const uint mw0 = *(const uint*)mask_raw;
    const bool mbytes = (mw0 == 0x01010101u);

    if (tid < 16) sCtl[tid] = 0;
    if (tid < 8) sS[14336 + tid] = 0;

    // per-lane byte selectors for v_perm l-extraction (pass-invariant)
    const uint selA = hi ? 0x03020302u : 0x01000100u;   // q = 0,2,4
    const uint selB = hi ? 0x05040504u : 0x03020302u;   // q = 1,3

    // ---- per-wave single-op T fragments ----
    half8v Tf[5];
    if constexpr (MODE == 1) {
        #pragma unroll
        for (int q = 0; q < 5; ++q) {
            union { uint4 u; half8v h; } z;
            z.u = tpk[(myOp * 5 + q) * 64 + lane];
            Tf[q] = z.h;
        }
    } else {
        #pragma unroll
        for (int q = 0; q < 5; ++q) {
            half8v t_;
            #pragma unroll
            for (int e = 0; e < 8; ++e) {
                int i = 5 * hi + q, j = jh + e;
                float v = 0.f;
                if (col < NI && j < NI)
                    v = op_table[myOp * 1000 + (i * NI + j) * NI + col] * LOG2E;
                t_[e] = (_Float16)v;
            }
            Tf[q] = t_;
        }
    }

    // ---- init state rows (both buffers) + capture node info (2 nodes/thread) ----
    int  myop0 = 3, myop1 = 3;
    uint enc0 = 0, enc1 = 0;
    #define INIT_NODE(N, MYOP, ENC)                                              \
    {                                                                            \
        int n = (N);                                                             \
        uint r[7] = {0, 0, 0, 0, 0, 0, 0};                                       \
        if (n < NN) {                                                            \
            int cat = cats[rowoff + n];                                          \
            int lit = lits[rowoff + n];                                          \
            int op  = ops[rowoff + n];                                           \
            int lf  = left[rowoff + n];                                          \
            int rt  = right[rowoff + n];                                         \
            bool m  = getmask(mask_raw, mbytes, rowoff + n);                     \
            lit = min(max(lit, 0), NI - 1);                                      \
            op  = min(max(op, 0), 2);                                            \
            lf  = min(max(lf, 0), NN - 1);                                       \
            rt  = min(max(rt, 0), NN - 1);                                       \
            if (cat == 0 && m) {                                                 \
                r[lit >> 1] = (lit & 1) ? 0x3C000000u : 0x3C00u;                 \
            } else if (cat == 1 && m) {                                          \
                MYOP = op;                                                       \
                ENC = (uint)n | ((uint)lf << 10) | ((uint)rt << 20);             \
            }                                                                    \
        }                                                                        \
        if (n < 1024) {                                                          \
            _Pragma("unroll")                                                    \
            for (int w = 0; w < 7; ++w) {                                        \
                sS[n * 7 + w] = r[w];                                            \
                sS[7168 + n * 7 + w] = r[w];                                     \
            }                                                                    \
        }                                                                        \
    }
    INIT_NODE(tid, myop0, enc0)
    INIT_NODE(tid + NTH, myop1, enc1)
    __syncthreads();

    // ---- ballot counting (1 atomic per op per wave) ----
    {
        ull m00 = __ballot(myop0 == 0), m01 = __ballot(myop0 == 1), m02 = __ballot(myop0 == 2);
        ull m10 = __ballot(myop1 == 0), m11 = __ballot(myop1 == 1), m12 = __ballot(myop1 == 2);
        int c0 = __popcll(m00) + __popcll(m10);
        int c1 = __popcll(m01) + __popcll(m11);
        int c2 = __popcll(m02) + __popcll(m12);
        if (lane == 0) {
            if (c0) atomicAdd(&sCtl[0], c0);
            if (c1) atomicAdd(&sCtl[1], c1);
            if (c2) atomicAdd(&sCtl[2], c2);
        }
    }
    __syncthreads();
    if (tid == 0) {
        int c0 = sCtl[0], c1 = sCtl[1], c2 = sCtl[2];
        int p0 = (c0 + 15) & ~15, p1 = (c1 + 15) & ~15, p2 = (c2 + 15) & ~15;
        sCtl[4] = p0; sCtl[5] = p0 + p1; sCtl[9] = p0 + p1 + p2;
        sCtl[6] = 0; sCtl[7] = p0; sCtl[8] = p0 + p1;   // cursors
    }
    __syncthreads();
    // ---- ballot placement ----
    #define PLACE(MYOP, ENC)                                                     \
    {                                                                            \
        _Pragma("unroll")                                                        \
        for (int o = 0; o < 3; ++o) {                                            \
            ull mm = __ballot((MYOP) == o);                                      \
            if (mm) {                                                            \
                int rsv = 0;                                                     \
                if (lane == 0) rsv = atomicAdd(&sCtl[6 + o], __popcll(mm));      \
                rsv = __shfl(rsv, 0);                                            \
                if ((MYOP) == o)                                                 \
                    sBkt[rsv + __popcll(mm & ((1ull << lane) - 1))] = (ENC);     \
            }                                                                    \
        }                                                                        \
    }
    PLACE(myop0, enc0)
    PLACE(myop1, enc1)
    __syncthreads();
    // ---- dummy-fill bucket tails ----
    {
        uint dv = (uint)DUMMY | ((uint)DUMMY << 10) | ((uint)DUMMY << 20);
        int f0 = sCtl[6], e0b = sCtl[4];
        int f1 = sCtl[7], e1b = sCtl[5];
        int f2 = sCtl[8], e2b = sCtl[9];
        if (tid < e0b - f0) sBkt[f0 + tid] = dv;
        if (tid < e1b - f1) sBkt[f1 + tid] = dv;
        if (tid < e2b - f2) sBkt[f2 + tid] = dv;
    }
    __syncthreads();

    const int tB1 = __builtin_amdgcn_readfirstlane(sCtl[4] >> 4);
    const int tB2 = __builtin_amdgcn_readfirstlane(sCtl[5] >> 4);
    const int tB3 = __builtin_amdgcn_readfirstlane(sCtl[9] >> 4);
    const int t_lo = (myOp == 0) ? 0   : ((myOp == 1) ? tB1 : tB2);
    const int t_hi = (myOp == 0) ? tB1 : ((myOp == 1) ? tB2 : tB3);
    const int first = t_lo + wl;
    const int nIter = (t_hi > first) ? ((t_hi - first + 3) >> 2) : 0;
    const int cat0 = cats[rowoff];
    const bool rootActive = (cat0 == 1) && getmask(mask_raw, mbytes, rowoff);

    // ---- cache <=3 iters of pass-invariant decoded byte offsets ----
    uint LA0 = 0, RA0 = 0, WA0 = 0, LA1 = 0, RA1 = 0, WA1 = 0, LA2 = 0, RA2 = 0, WA2 = 0;
    bool RT0 = false, RT1 = false, RT2 = false;
    #define CACHE1(K, LA, RA, WA, RT)                                            \
    if (nIter > K) {                                                             \
        uint E = sBkt[(first + K * 4) * 16 + col];                               \
        uint n_ = E & 1023u, lf_ = (E >> 10) & 1023u, rt_ = (E >> 20) & 1023u;   \
        LA = lf_ * 28u + 8u * (uint)hi;                                          \
        RA = rt_ * 28u + 2u * (uint)jh;                                          \
        WA = n_ * 28u + 8u * (uint)g;                                            \
        RT = (n_ == 0u);                                                         \
    }
    CACHE1(0, LA0, RA0, WA0, RT0)
    CACHE1(1, LA1, RA1, WA1, RT1)
    CACHE1(2, LA2, RA2, WA2, RT2)

    char* sbase = (char*)&sS[0];

    #define MSTQ(QI, LU) {                                                       \
        half2v l2v = h2(LU);                                                     \
        union { half8v v8; half2v v2[4]; } au;                                   \
        au.v2[0] = l2v * R0; au.v2[1] = l2v * R1;                                \
        au.v2[2] = l2v * R2; au.v2[3] = l2v * R3;                                \
        C = __builtin_amdgcn_mfma_f32_16x16x32_f16(Tf[QI], au.v8, C, 0, 0, 0);   \
    }
    // passes 0..8: compute + softmax + state write (no root logic)
    #define ITER_BODY(LA, RA, WA)                                                \
    {                                                                            \
        const uint* lpd = (const uint*)(rbase + (LA));                           \
        const uint* rp  = (const uint*)(rbase + (RA));                           \
        uint D0 = lpd[0], D1 = lpd[1], D2 = lpd[2];                              \
        half2v R0 = h2(rp[0]), R1 = h2(rp[1]), R2 = h2(rp[2]), R3 = h2(rp[3]);   \
        uint L0 = __builtin_amdgcn_perm(D0, D0, selA);                           \
        uint L1 = __builtin_amdgcn_perm(D1, D0, selB);                           \
        uint L2 = __builtin_amdgcn_perm(D1, D1, selA);                           \
        uint L3 = __builtin_amdgcn_perm(D2, D1, selB);                           \
        uint L4 = __builtin_amdgcn_perm(D2, D2, selA);                           \
        floatx4 C = {0.f, 0.f, 0.f, 0.f};                                        \
        MSTQ(0, L0) MSTQ(1, L1) MSTQ(2, L2) MSTQ(3, L3) MSTQ(4, L4)              \
        float e0 = 0.f, e1 = 0.f, e2 = 0.f, e3 = 0.f, part;                      \
        if (g < 2) {                                                             \
            e0 = EXP2(C[0]); e1 = EXP2(C[1]); e2 = EXP2(C[2]); e3 = EXP2(C[3]);  \
            part = (e0 + e1) + (e2 + e3);                                        \
        } else if (g == 2) {                                                     \
            e0 = EXP2(C[0]); e1 = EXP2(C[1]); part = e0 + e1;                    \
        } else part = 0.f;                                                       \
        REDUCE16_32(part)                                                        \
        float inv = RCP(part);                                                   \
        if (g < 2) {                                                             \
            uint* wp = (uint*)(wbase + (WA));                                    \
            wp[0] = pkh(e0 * inv, e1 * inv);                                     \
            wp[1] = pkh(e2 * inv, e3 * inv);                                     \
        } else if (g == 2) {                                                     \
            *(uint*)(wbase + (WA)) = pkh(e0 * inv, e1 * inv);                    \
        }                                                                        \
    }
    // final pass: logits only (state write is dead), root store
    #define ITER_LAST(LA, RA, RT)                                                \
    {                                                                            \
        const uint* lpd = (const uint*)(rbase + (LA));                           \
        const uint* rp  = (const uint*)(rbase + (RA));                           \
        uint D0 = lpd[0], D1 = lpd[1], D2 = lpd[2];                              \
        half2v R0 = h2(rp[0]), R1 = h2(rp[1]), R2 = h2(rp[2]), R3 = h2(rp[3]);   \
        uint L0 = __builtin_amdgcn_perm(D0, D0, selA);                           \
        uint L1 = __builtin_amdgcn_perm(D1, D0, selB);                           \
        uint L2 = __builtin_amdgcn_perm(D1, D1, selA);                           \
        uint L3 = __builtin_amdgcn_perm(D2, D1, selB);                           \
        uint L4 = __builtin_amdgcn_perm(D2, D2, selA);                           \
        floatx4 C = {0.f, 0.f, 0.f, 0.f};                                        \
        MSTQ(0, L0) MSTQ(1, L1) MSTQ(2, L2) MSTQ(3, L3) MSTQ(4, L4)              \
        if (RT) {                                                                \
            if (g < 2) {                                                         \
                out[b * NI + 4 * g + 0] = C[0] * LN2;                            \
                out[b * NI + 4 * g + 1] = C[1] * LN2;                            \
                out[b * NI + 4 * g + 2] = C[2] * LN2;                            \
                out[b * NI + 4 * g + 3] = C[3] * LN2;                            \
            } else if (g == 2) {                                                 \
                out[b * NI + 8] = C[0] * LN2;                                    \
                out[b * NI + 9] = C[1] * LN2;                                    \
            }                                                                    \
        }                                                                        \
    }

    for (int p = 0; p < NPASS - 1; ++p) {
        char* rbase = sbase + ((p & 1) ? SBYTES : 0);
        char* wbase = sbase + ((p & 1) ? 0 : SBYTES);

        if (nIter > 0) ITER_BODY(LA0, RA0, WA0)
        if (nIter > 1) ITER_BODY(LA1, RA1, WA1)
        if (nIter > 2) ITER_BODY(LA2, RA2, WA2)
        for (int it = 3; it < nIter; ++it) {     // rare overflow
            uint E = sBkt[(first + it * 4) * 16 + col];
            uint n_ = E & 1023u, lf_ = (E >> 10) & 1023u, rt_ = (E >> 20) & 1023u;
            uint LAx = lf_ * 28u + 8u * (uint)hi;
            uint RAx = rt_ * 28u + 2u * (uint)jh;
            uint WAx = n_ * 28u + 8u * (uint)g;
            ITER_BODY(LAx, RAx, WAx)
        }
        __syncthreads();   // single barrier per pass (ping-pong)
    }
    {
        // pass 9: reads buffer 1 (state after 9 updates); root logits only.
        // Only the tile containing node 0 has any side effect -> wave-uniform
        // ballot skip eliminates ~97% of pass-9 work.
        char* rbase = sbase + SBYTES;
        if (nIter > 0 && __ballot(RT0)) ITER_LAST(LA0, RA0, RT0)
        if (nIter > 1 && __ballot(RT1)) ITER_LAST(LA1, RA1, RT1)
        if (nIter > 2 && __ballot(RT2)) ITER_LAST(LA2, RA2, RT2)
        for (int it = 3; it < nIter; ++it) {
            uint E = sBkt[(first + it * 4) * 16 + col];
            uint n_ = E & 1023u, lf_ = (E >> 10) & 1023u, rt_ = (E >> 20) & 1023u;
            uint LAx = lf_ * 28u + 8u * (uint)hi;
            uint RAx = rt_ * 28u + 2u * (uint)jh;
            bool RTx = (n_ == 0u);
            if (__ballot(RTx)) ITER_LAST(LAx, RAx, RTx)
        }
    }

    // masked-out op-root: logits from state-after-9 (= buffer 1)
    if (cat0 == 1 && !rootActive && tid == 0) {
        int op0 = min(max(ops[rowoff], 0), 2);
        int lf0 = min(max(left[rowoff], 0), NN - 1);
        int rt0 = min(max(right[rowoff], 0), NN - 1);
        const _Float16* sh = (const _Float16*)((char*)sS + SBYTES);
        float acc[NI];
        #pragma unroll
        for (int k = 0; k < NI; ++k) acc[k] = 0.f;
        for (int i = 0; i < NI; ++i) {
            float li = (float)sh[lf0 * 14 + i];
            for (int j = 0; j < NI; ++j) {
                float w = li * (float)sh[rt0 * 14 + j];
                #pragma unroll
                for (int k = 0; k < NI; ++k)
                    acc[k] = fmaf(w, op_table[op0 * 1000 + (i * NI + j) * NI + k], acc[k]);
            }
        }
        #pragma unroll
        for (int k = 0; k < NI; ++k) out[b * NI + k] = acc[k];
    }

    // lit-cat root: init state persists (lit rows never rewritten)
    if (cat0 == 0 && tid < NI) {
        out[b * NI + tid] = (float)((const _Float16*)sS)[tid] * 10.f;
    }
}

extern "C" void kernel_launch(void* const* d_in, const int* in_sizes, int n_in,
                              void* d_out, int out_size, void* d_ws, size_t ws_size,
                              hipStream_t stream) {
    const float* op_table = (const float*)d_in[0];
    const int*   cats     = (const int*)d_in[1];
    const int*   ops      = (const int*)d_in[2];
    const int*   lits     = (const int*)d_in[3];
    const int*   left     = (const int*)d_in[4];
    const int*   right    = (const int*)d_in[5];
    const void*  mask     = d_in[6];
    float* out = (float*)d_out;

    const size_t tbytes = (size_t)15 * 64 * sizeof(uint4);   // 15,360

    if (ws_size >= tbytes) {
        uint4* tpk = (uint4*)d_ws;
        prepack_kernel<<<dim3(15), dim3(64), 0, stream>>>(op_table, tpk);
        circuit_kernel<1><<<dim3(BB), dim3(NTH), 0, stream>>>(
            op_table, cats, ops, lits, left, right, mask, out, tpk);
    } else {
        circuit_kernel<0><<<dim3(BB), dim3(NTH), 0, stream>>>(
            op_table, cats, ops, lits, left, right, mask, out, nullptr);
    }
}